// Round 4
// baseline (66.819 us; speedup 1.0000x reference)
//
#include <hip/hip_runtime.h>
#include <cmath>

#define B_N 512
#define T_N 50
#define GRIDN 13
#define A_N 9
#define P_N 1521          // 13*13*9
#define ROW 85            // 5 + 80 classes
#define NCLS 80
#define CHUNKS 4
#define CH_P 381          // ceil(1521/4)

struct Entry {
    int prior;
    float tx, ty, tw, th;
    unsigned int cls[3];   // 80-bit class one-hot mask
};                          // 32 bytes

// ---------------------------------------------------------------------------
// Main kernel: grid = (CHUNKS, B). blockIdx.y = image, blockIdx.x = chunk.
//   All blocks:    scan their 381-prior slice of the conf column.
//   Chunk-0 block: additionally builds the entry list (wave 0, shfl dedup)
//                  and does the obj-prior corrections (cls BCE / obj / box).
// Each block writes one partial; no global atomics.
// ---------------------------------------------------------------------------
__global__ void __launch_bounds__(256)
main_kernel(const float* __restrict__ pred,
            const float* __restrict__ tgt,
            const float* __restrict__ anchors,
            float* __restrict__ S_part,   // [B][CHUNKS]
            float* __restrict__ corr)     // [B][4]: BX, LP, L1, CL
{
    __shared__ Entry ents[T_N];
    __shared__ float red[4][5];
    __shared__ int   s_cnt;

    const int  tid  = threadIdx.x;
    const int  lane = tid & 63;
    const int  b    = blockIdx.y;
    const int  c    = blockIdx.x;
    const bool isc0 = (c == 0);

    // ---------------- Phase A (wave 0) ----------------
    if (tid < 64) {
        if (isc0) {
            int   prior = -1;
            float txv = 0.f, tyv = 0.f, twv = 0.f, thv = 0.f;
            int   cls = 0;
            if (lane < T_N) {
                const float* t = tgt + ((size_t)b * T_N + lane) * 6;
                float x = t[0], y = t[1], w = t[2], h = t[3], conf = t[4];
                if (conf > 0.0f) {
                    float tw_px = w * 1000.0f, th_px = h * 1000.0f;
                    int best = 0; float bestv = -1.0f;
                    #pragma unroll
                    for (int a = 0; a < A_N; ++a) {
                        float aw = anchors[2*a], ah = anchors[2*a+1];
                        float inter = fminf(aw, tw_px) * fminf(ah, th_px);
                        float uni   = aw*ah + tw_px*th_px - inter;
                        float iou   = inter / (uni + 1e-16f);
                        if (iou > bestv) { bestv = iou; best = a; }  // first-max
                    }
                    int gx = (int)floorf(x * (float)GRIDN);
                    int gy = (int)floorf(y * (float)GRIDN);
                    prior = gy * (GRIDN * A_N) + gx * A_N + best;
                    txv = x * (float)GRIDN - (float)gx;
                    tyv = y * (float)GRIDN - (float)gy;
                    float aw = anchors[2*best], ah = anchors[2*best+1];
                    twv = logf(w * (float)GRIDN / aw + 1e-16f);
                    thv = logf(h * (float)GRIDN / ah + 1e-16f);
                    cls = (int)t[5];
                }
            }
            bool valid = (prior >= 0);
            unsigned int m0 = 0, m1 = 0, m2 = 0;
            bool laterdup = false;
            #pragma unroll
            for (int j = 0; j < T_N; ++j) {
                int pj = __shfl(prior, j, 64);
                int cj = __shfl(cls,   j, 64);
                if (valid && pj == prior) {
                    if (j > lane) laterdup = true;   // last-wins scatter
                    if (cj < 32)      m0 |= 1u << cj;
                    else if (cj < 64) m1 |= 1u << (cj - 32);
                    else              m2 |= 1u << (cj - 64);
                }
            }
            bool winner = valid && !laterdup;
            unsigned long long mask = __ballot(winner);
            if (winner) {
                int idx = __popcll(mask & ((1ull << lane) - 1ull));
                Entry* e = &ents[idx];
                e->prior = prior;
                e->tx = txv; e->ty = tyv; e->tw = twv; e->th = thv;
                e->cls[0] = m0; e->cls[1] = m1; e->cls[2] = m2;
            }
            if (lane == 0) s_cnt = __popcll(mask);
        } else {
            // only need the has-any-target flag
            float conf = (lane < T_N) ? tgt[((size_t)b * T_N + lane) * 6 + 4] : 0.0f;
            unsigned long long m = __ballot(conf > 0.0f);
            if (lane == 0) s_cnt = (m != 0ull) ? 1 : 0;
        }
    }
    __syncthreads();

    const int  cnt  = s_cnt;
    const bool hasv = (cnt > 0);

    // ---------------- Phase B: conf-column slice ----------------
    const float* pb = pred + (size_t)b * P_N * ROW;
    const int p0 = c * CH_P;
    const int p1 = (p0 + CH_P < P_N) ? p0 + CH_P : P_N;
    float s_main = 0.0f;
    for (int p = p0 + tid; p < p1; p += 256) {
        float x = pb[(size_t)p * ROW + 4];
        float s = 1.0f / (1.0f + __expf(-x));
        s_main += hasv ? fmaxf(__logf(1.0f - s), -100.0f)
                       : fmaxf(__logf(s),        -100.0f);
    }

    // ---------------- Phase C: obj corrections (chunk 0 only) ----------------
    float cls_s = 0.0f, box_s = 0.0f, objlp = 0.0f, objl1 = 0.0f;
    if (isc0) {
        const int half = tid >> 7;      // 0 or 1
        const int lt   = tid & 127;
        for (int e = half; e < cnt; e += 2) {
            Entry en = ents[e];
            const float* row = pb + (size_t)en.prior * ROW;
            if (lt < NCLS) {
                float x  = row[5 + lt];
                float s  = 1.0f / (1.0f + __expf(-x));
                float lp = fmaxf(__logf(s),        -100.0f);
                float l1 = fmaxf(__logf(1.0f - s), -100.0f);
                float tc = ((en.cls[lt >> 5] >> (lt & 31)) & 1u) ? 1.0f : 0.0f;
                cls_s += -(tc * lp + (1.0f - tc) * l1);
            } else if (lt == NCLS) {
                float x = row[4];
                float s = 1.0f / (1.0f + __expf(-x));
                objlp += fmaxf(__logf(s),        -100.0f);
                objl1 += fmaxf(__logf(1.0f - s), -100.0f);
            } else if (lt == NCLS + 1) {
                float d0 = row[0] - en.tx;
                float d1 = row[1] - en.ty;
                float d2 = row[2] - en.tw;
                float d3 = row[3] - en.th;
                box_s += d0*d0 + d1*d1 + d2*d2 + d3*d3;
            }
        }
    }

    // ---------------- Epilogue: block reduce ----------------
    float v0 = s_main, v1 = objl1, v2 = objlp, v3 = box_s, v4 = cls_s;
    #pragma unroll
    for (int o = 32; o > 0; o >>= 1) {
        v0 += __shfl_down(v0, o, 64);
        v1 += __shfl_down(v1, o, 64);
        v2 += __shfl_down(v2, o, 64);
        v3 += __shfl_down(v3, o, 64);
        v4 += __shfl_down(v4, o, 64);
    }
    const int w = tid >> 6;
    if (lane == 0) {
        red[w][0] = v0; red[w][1] = v1; red[w][2] = v2;
        red[w][3] = v3; red[w][4] = v4;
    }
    __syncthreads();
    if (tid == 0) {
        float S = red[0][0] + red[1][0] + red[2][0] + red[3][0];
        S_part[(b << 2) + c] = S;
        if (isc0) {
            float L1 = red[0][1] + red[1][1] + red[2][1] + red[3][1];
            float LP = red[0][2] + red[1][2] + red[2][2] + red[3][2];
            float BX = red[0][3] + red[1][3] + red[2][3] + red[3][3];
            float CL = red[0][4] + red[1][4] + red[2][4] + red[3][4];
            float* o = corr + (size_t)b * 4;
            o[0] = BX; o[1] = LP; o[2] = L1; o[3] = CL;
        }
    }
}

// ---------------------------------------------------------------------------
// Finalize: reduce 512 images' partials -> 5 outputs.
// ---------------------------------------------------------------------------
__global__ void __launch_bounds__(256)
finalize_kernel(const float* __restrict__ S_part,
                const float* __restrict__ corr,
                float* __restrict__ out)
{
    __shared__ float red[4][4];
    const int tid  = threadIdx.x;
    const int lane = tid & 63;

    float a_box = 0, a_obj = 0, a_noobj = 0, a_cls = 0;
    for (int b = tid; b < B_N; b += 256) {
        float4 s4 = ((const float4*)S_part)[b];
        float  S  = (s4.x + s4.y) + (s4.z + s4.w);
        float4 cr = ((const float4*)corr)[b];     // BX, LP, L1, CL
        a_box   += 5.0f * cr.x;
        a_obj   += -cr.y;
        a_noobj += -100.0f * (S - cr.z);
        a_cls   += cr.w;
    }
    #pragma unroll
    for (int o = 32; o > 0; o >>= 1) {
        a_box   += __shfl_down(a_box,   o, 64);
        a_obj   += __shfl_down(a_obj,   o, 64);
        a_noobj += __shfl_down(a_noobj, o, 64);
        a_cls   += __shfl_down(a_cls,   o, 64);
    }
    const int w = tid >> 6;
    if (lane == 0) { red[w][0] = a_box; red[w][1] = a_obj; red[w][2] = a_noobj; red[w][3] = a_cls; }
    __syncthreads();
    if (tid == 0) {
        const float invB = 1.0f / (float)B_N;
        float box   = (red[0][0] + red[1][0] + red[2][0] + red[3][0]) * invB;
        float obj   = (red[0][1] + red[1][1] + red[2][1] + red[3][1]) * invB;
        float noobj = (red[0][2] + red[1][2] + red[2][2] + red[3][2]) * invB;
        float cls   = (red[0][3] + red[1][3] + red[2][3] + red[3][3]) * invB;
        out[0] = box + obj + noobj + cls;
        out[1] = box;
        out[2] = obj;
        out[3] = noobj;
        out[4] = cls;
    }
}

extern "C" void kernel_launch(void* const* d_in, const int* in_sizes, int n_in,
                              void* d_out, int out_size, void* d_ws, size_t ws_size,
                              hipStream_t stream)
{
    const float* pred    = (const float*)d_in[0];  // [512,1521,85]
    const float* tgt     = (const float*)d_in[1];  // [512,50,6]
    const float* anchors = (const float*)d_in[2];  // [9,2]
    float* out = (float*)d_out;                    // 5 floats

    char*  ws     = (char*)d_ws;
    float* S_part = (float*)ws;                    // 512*4 floats = 8 KiB
    float* corr   = (float*)(ws + 8192);           // 512*4 floats = 8 KiB

    main_kernel<<<dim3(CHUNKS, B_N), dim3(256), 0, stream>>>(pred, tgt, anchors, S_part, corr);
    finalize_kernel<<<dim3(1), dim3(256), 0, stream>>>(S_part, corr, out);
}

// Round 5
// 54.720 us; speedup vs baseline: 1.2211x; 1.2211x over previous
//
#include <hip/hip_runtime.h>
#include <cmath>

#define B_N 512
#define T_N 50
#define GRIDN 13
#define A_N 9
#define P_N 1521          // 13*13*9
#define ROW 85            // 5 + 80 classes
#define NCLS 80
#define FPI (P_N * ROW)   // floats per image = 129285
#define NTHR 1024

struct Entry {
    int prior;
    float tx, ty, tw, th;
    unsigned int cls[3];   // 80-bit class one-hot mask
};

// ---------------------------------------------------------------------------
// Main kernel: one block (1024 thr) per image.
//   Step 1: per-wave has-flag via ballot (no barrier).
//   Step 2: dense float4 stream of the whole 517KB slab; extract col-4 (conf)
//           arithmetically and accumulate S_main. BW-bound by design.
//   Step 3: wave 0 builds the entry list (shfl dedup, last-wins).
//   Step 4: 8 groups x 128 thr: obj-prior corrections (cls BCE / obj / box),
//           re-reading the ~28 obj rows from global (~6 lines each).
//   Epilogue: block reduce 5 sums -> part[b][5]. No atomics.
// ---------------------------------------------------------------------------
__global__ void __launch_bounds__(NTHR)
main_kernel(const float* __restrict__ pred,
            const float* __restrict__ tgt,
            const float* __restrict__ anchors,
            float* __restrict__ part)      // [B][5]: S, L1, LP, BX, CL
{
    __shared__ Entry ents[T_N];
    __shared__ int   s_cnt;
    __shared__ float red[16][5];

    const int tid  = threadIdx.x;
    const int lane = tid & 63;
    const int b    = blockIdx.x;

    // ---------------- Step 1: per-wave has flag ----------------
    const float* tb = tgt + (size_t)b * T_N * 6;
    float confv = (lane < T_N) ? tb[lane * 6 + 4] : 0.0f;
    const bool hasv = (__ballot(confv > 0.0f) != 0ull);

    // ---------------- Step 2: dense conf stream ----------------
    // slab start is (b%4) floats off 16B; skip a0 head floats (cols 0..2 of
    // row 0) and the <4-float tail (cols 82..84 of row 1520) — never col 4.
    const float* slab = pred + (size_t)b * FPI;
    const int a0 = (4 - (b & 3)) & 3;
    const int NQ = (FPI - a0) >> 2;
    const float4* qp = (const float4*)(slab + a0);
    float s_main = 0.0f;
    for (int q = tid; q < NQ; q += NTHR) {
        float4 v = qp[q];
        int f0 = a0 + (q << 2);
        int c0 = f0 % 85;                       // col of element 0 of quad
        if ((unsigned)(c0 - 1) <= 3u) {         // quad contains col 4 at k=4-c0
            int k = 4 - c0;
            float x = (k == 0) ? v.x : (k == 1) ? v.y : (k == 2) ? v.z : v.w;
            float s = 1.0f / (1.0f + __expf(-x));
            s_main += hasv ? fmaxf(__logf(1.0f - s), -100.0f)
                           : fmaxf(__logf(s),        -100.0f);
        }
    }

    // ---------------- Step 3: entry build (wave 0) ----------------
    if (tid < 64) {
        int   prior = -1;
        float txv = 0.f, tyv = 0.f, twv = 0.f, thv = 0.f;
        int   cls = 0;
        if (lane < T_N) {
            const float* t = tb + lane * 6;
            float x = t[0], y = t[1], w = t[2], h = t[3], conf = t[4];
            if (conf > 0.0f) {
                float tw_px = w * 1000.0f, th_px = h * 1000.0f;
                int best = 0; float bestv = -1.0f;
                #pragma unroll
                for (int a = 0; a < A_N; ++a) {
                    float aw = anchors[2*a], ah = anchors[2*a+1];
                    float inter = fminf(aw, tw_px) * fminf(ah, th_px);
                    float uni   = aw*ah + tw_px*th_px - inter;
                    float iou   = inter / (uni + 1e-16f);
                    if (iou > bestv) { bestv = iou; best = a; }  // first-max
                }
                int gx = (int)floorf(x * (float)GRIDN);
                int gy = (int)floorf(y * (float)GRIDN);
                prior = gy * (GRIDN * A_N) + gx * A_N + best;
                txv = x * (float)GRIDN - (float)gx;
                tyv = y * (float)GRIDN - (float)gy;
                float aw = anchors[2*best], ah = anchors[2*best+1];
                twv = logf(w * (float)GRIDN / aw + 1e-16f);
                thv = logf(h * (float)GRIDN / ah + 1e-16f);
                cls = (int)t[5];
            }
        }
        bool valid = (prior >= 0);
        unsigned int m0 = 0, m1 = 0, m2 = 0;
        bool laterdup = false;
        #pragma unroll
        for (int j = 0; j < T_N; ++j) {
            int pj = __shfl(prior, j, 64);
            int cj = __shfl(cls,   j, 64);
            if (valid && pj == prior) {
                if (j > lane) laterdup = true;   // last-wins scatter
                if (cj < 32)      m0 |= 1u << cj;
                else if (cj < 64) m1 |= 1u << (cj - 32);
                else              m2 |= 1u << (cj - 64);
            }
        }
        bool winner = valid && !laterdup;
        unsigned long long mask = __ballot(winner);
        if (winner) {
            int idx = __popcll(mask & ((1ull << lane) - 1ull));
            Entry* e = &ents[idx];
            e->prior = prior;
            e->tx = txv; e->ty = tyv; e->tw = twv; e->th = thv;
            e->cls[0] = m0; e->cls[1] = m1; e->cls[2] = m2;
        }
        if (lane == 0) s_cnt = __popcll(mask);
    }
    __syncthreads();

    const int cnt = s_cnt;

    // ---------------- Step 4: obj corrections (8 groups of 128) ----------
    float cls_s = 0.0f, box_s = 0.0f, objlp = 0.0f, objl1 = 0.0f;
    {
        const int gid = tid >> 7;       // 0..7
        const int lt  = tid & 127;
        for (int e = gid; e < cnt; e += 8) {
            Entry en = ents[e];
            const float* row = slab + (size_t)en.prior * ROW;
            if (lt < NCLS) {
                float x  = row[5 + lt];
                float s  = 1.0f / (1.0f + __expf(-x));
                float lp = fmaxf(__logf(s),        -100.0f);
                float l1 = fmaxf(__logf(1.0f - s), -100.0f);
                float tc = ((en.cls[lt >> 5] >> (lt & 31)) & 1u) ? 1.0f : 0.0f;
                cls_s += -(tc * lp + (1.0f - tc) * l1);
            } else if (lt == NCLS) {
                float x = row[4];
                float s = 1.0f / (1.0f + __expf(-x));
                objlp += fmaxf(__logf(s),        -100.0f);
                objl1 += fmaxf(__logf(1.0f - s), -100.0f);
            } else if (lt == NCLS + 1) {
                float d0 = row[0] - en.tx;
                float d1 = row[1] - en.ty;
                float d2 = row[2] - en.tw;
                float d3 = row[3] - en.th;
                box_s += d0*d0 + d1*d1 + d2*d2 + d3*d3;
            }
        }
    }

    // ---------------- Epilogue: block reduce 5 sums ----------------
    float v0 = s_main, v1 = objl1, v2 = objlp, v3 = box_s, v4 = cls_s;
    #pragma unroll
    for (int o = 32; o > 0; o >>= 1) {
        v0 += __shfl_down(v0, o, 64);
        v1 += __shfl_down(v1, o, 64);
        v2 += __shfl_down(v2, o, 64);
        v3 += __shfl_down(v3, o, 64);
        v4 += __shfl_down(v4, o, 64);
    }
    const int w = tid >> 6;
    if (lane == 0) {
        red[w][0] = v0; red[w][1] = v1; red[w][2] = v2;
        red[w][3] = v3; red[w][4] = v4;
    }
    __syncthreads();
    if (tid < 5) {
        float s = 0.0f;
        #pragma unroll
        for (int ww = 0; ww < 16; ++ww) s += red[ww][tid];
        part[(size_t)b * 5 + tid] = s;        // S, L1, LP, BX, CL
    }
}

// ---------------------------------------------------------------------------
// Finalize: reduce 512 images' partials -> 5 outputs.
// ---------------------------------------------------------------------------
__global__ void __launch_bounds__(256)
finalize_kernel(const float* __restrict__ part, float* __restrict__ out)
{
    __shared__ float red[4][4];
    const int tid  = threadIdx.x;
    const int lane = tid & 63;

    float a_box = 0, a_obj = 0, a_noobj = 0, a_cls = 0;
    for (int b = tid; b < B_N; b += 256) {
        const float* p = part + (size_t)b * 5;
        float S  = p[0];
        float L1 = p[1];
        float LP = p[2];
        float BX = p[3];
        float CL = p[4];
        a_box   += 5.0f * BX;
        a_obj   += -LP;
        a_noobj += -100.0f * (S - L1);   // valid for empty branch too (L1==0)
        a_cls   += CL;
    }
    #pragma unroll
    for (int o = 32; o > 0; o >>= 1) {
        a_box   += __shfl_down(a_box,   o, 64);
        a_obj   += __shfl_down(a_obj,   o, 64);
        a_noobj += __shfl_down(a_noobj, o, 64);
        a_cls   += __shfl_down(a_cls,   o, 64);
    }
    const int w = tid >> 6;
    if (lane == 0) { red[w][0] = a_box; red[w][1] = a_obj; red[w][2] = a_noobj; red[w][3] = a_cls; }
    __syncthreads();
    if (tid == 0) {
        const float invB = 1.0f / (float)B_N;
        float box   = (red[0][0] + red[1][0] + red[2][0] + red[3][0]) * invB;
        float obj   = (red[0][1] + red[1][1] + red[2][1] + red[3][1]) * invB;
        float noobj = (red[0][2] + red[1][2] + red[2][2] + red[3][2]) * invB;
        float cls   = (red[0][3] + red[1][3] + red[2][3] + red[3][3]) * invB;
        out[0] = box + obj + noobj + cls;
        out[1] = box;
        out[2] = obj;
        out[3] = noobj;
        out[4] = cls;
    }
}

extern "C" void kernel_launch(void* const* d_in, const int* in_sizes, int n_in,
                              void* d_out, int out_size, void* d_ws, size_t ws_size,
                              hipStream_t stream)
{
    const float* pred    = (const float*)d_in[0];  // [512,1521,85]
    const float* tgt     = (const float*)d_in[1];  // [512,50,6]
    const float* anchors = (const float*)d_in[2];  // [9,2]
    float* out  = (float*)d_out;                   // 5 floats
    float* part = (float*)d_ws;                    // 512*5 floats

    main_kernel<<<dim3(B_N), dim3(NTHR), 0, stream>>>(pred, tgt, anchors, part);
    finalize_kernel<<<dim3(1), dim3(256), 0, stream>>>(part, out);
}